// Round 9
// baseline (192.420 us; speedup 1.0000x reference)
//
#include <hip/hip_runtime.h>
#include <math.h>

// Problem constants
#define BB   8
#define SS   100
#define TT   1200        // S * DMAX
#define NM   80          // NMEL
#define DMC  128         // DM
#define KK   9
#define G3   384         // 3*DM
#define NROW (BB*TT)     // 9600

typedef __attribute__((ext_vector_type(8))) short short8;
typedef __attribute__((ext_vector_type(4))) float f32x4;

__device__ __forceinline__ float sigmoid_(float v) { return 1.f / (1.f + __expf(-v)); }
__device__ __forceinline__ float tanh_(float v) {
    float a = fabsf(v);
    float e = __expf(-2.f * a);
    float t = (1.f - e) / (1.f + e);
    return copysignf(t, v);
}
__device__ __forceinline__ unsigned short f2bf(float f) {   // RNE fp32->bf16
    unsigned int u = __float_as_uint(f);
    unsigned int r = (u + 0x7fffu + ((u >> 16) & 1u)) >> 16;
    return (unsigned short)r;
}

// ---------------------------------------------------------------------------
// Kernel P (fused prep), 24 blocks x 1024 thr:
//   blk 0..11  : pack w_hh into A-frag split-bf16
//   blk 12..20 : pack w_ih into A-frag split-bf16
//   blk 21     : durations prefix-scan -> starts; concat biases
//   blk 22     : pack w1 (BN1 scale folded) into conv1 A-frags, K=9 pad 32
//   blk 23     : pack w2^T into conv2 A-frags (M=k' pad 16, K=d=128)
// A-frag (16x16x32 bf16): lane holds A[m=lane&15][k=(lane>>4)*8 + j], j=0..7
// ---------------------------------------------------------------------------
__global__ __launch_bounds__(1024) void k_prep(
    const float* __restrict__ whf, const float* __restrict__ whb,
    const float* __restrict__ wif, const float* __restrict__ wib,
    const float* __restrict__ bf, const float* __restrict__ bbv,
    const int* __restrict__ dur,
    const float* __restrict__ w1, const float* __restrict__ g1,
    const float* __restrict__ w2,
    unsigned short* __restrict__ wph, unsigned short* __restrict__ wpl,
    unsigned short* __restrict__ wih_h, unsigned short* __restrict__ wih_l,
    float* __restrict__ biasc, int* __restrict__ starts,
    unsigned short* __restrict__ w1fh, unsigned short* __restrict__ w1fl,
    unsigned short* __restrict__ w2th, unsigned short* __restrict__ w2tl) {
    int blk = blockIdx.x;
    int tid = threadIdx.x;
    if (blk < 12) {
        int idx = blk * 1024 + tid;           // [0, 12288)
        int lane = idx & 63;
        int k32  = (idx >> 6) & 3;
        int tau  = (idx >> 8) % 24;
        int dir  = idx / (24 * 4 * 64);
        const float* w = dir ? whb : whf;
        int g = tau * 16 + (lane & 15);
        int kbase = k32 * 32 + (lane >> 4) * 8;
#pragma unroll
        for (int j = 0; j < 8; j++) {
            float v = w[g * DMC + kbase + j];
            unsigned short hi = f2bf(v);
            float hif = __uint_as_float(((unsigned)hi) << 16);
            unsigned short lo = f2bf(v - hif);
            wph[idx * 8 + j] = hi;
            wpl[idx * 8 + j] = lo;
        }
    } else if (blk < 21) {
        int idx = (blk - 12) * 1024 + tid;    // [0, 9216)
        int lane = idx & 63;
        int ks   = (idx >> 6) % 3;
        int tau  = idx / (3 * 64);
        int gate = tau * 16 + (lane & 15);
        int kb   = ks * 32 + (lane >> 4) * 8;
        const float* w = (gate < G3) ? (wif + gate * NM) : (wib + (gate - G3) * NM);
#pragma unroll
        for (int j = 0; j < 8; j++) {
            int k = kb + j;
            float v = (k < NM) ? w[k] : 0.f;
            unsigned short hi = f2bf(v);
            float hif = __uint_as_float(((unsigned)hi) << 16);
            unsigned short lo = f2bf(v - hif);
            wih_h[idx * 8 + j] = hi;
            wih_l[idx * 8 + j] = lo;
        }
    } else if (blk == 21) {
        __shared__ int buf[BB][128];
        int s = tid & 127, b = tid >> 7;
        int v = (s < SS) ? dur[b * SS + s] : 0;
        buf[b][s] = v;
        __syncthreads();
        for (int off = 1; off < 128; off <<= 1) {
            int t = (s >= off) ? buf[b][s - off] : 0;
            __syncthreads();
            buf[b][s] += t;
            __syncthreads();
        }
        if (s < SS) starts[b * SS + s] = buf[b][s] - v;
        if (tid < 768) biasc[tid] = (tid < G3) ? bf[tid] : bbv[tid - G3];
    } else if (blk == 22) {
        // conv1 A-frags: M=d (8 tiles), K=taps (9 pad 32), scale folded
        if (tid < 512) {
            int dt = tid >> 6, lane = tid & 63;
            int d = dt * 16 + (lane & 15);
            float sc = g1[d] * 0.9999950000374997f;
#pragma unroll
            for (int j = 0; j < 8; j++) {
                int k = (lane >> 4) * 8 + j;
                float v = (k < KK) ? w1[d * KK + k] * sc : 0.f;
                unsigned short hi = f2bf(v);
                float hif = __uint_as_float(((unsigned)hi) << 16);
                w1fh[tid * 8 + j] = hi;
                w1fl[tid * 8 + j] = f2bf(v - hif);
            }
        }
    } else {
        // conv2 A-frags: M=k' (1 tile of 16, k'>=9 zero), K=d (4 steps of 32)
        if (tid < 256) {
            int k32 = tid >> 6, lane = tid & 63;
            int kp = lane & 15;
#pragma unroll
            for (int j = 0; j < 8; j++) {
                int d = k32 * 32 + (lane >> 4) * 8 + j;
                float v = (kp < KK) ? w2[d * KK + kp] : 0.f;
                unsigned short hi = f2bf(v);
                float hif = __uint_as_float(((unsigned)hi) << 16);
                w2th[tid * 8 + j] = hi;
                w2tl[tid * 8 + j] = f2bf(v - hif);
            }
        }
    }
}

// ---------------------------------------------------------------------------
// Kernel A (R9): conv via MFMA. One (b,t) row per block, 256 thr (4 waves).
// conv1: C[d][m] = w1sc(128x9) x im2col(mel)(9pad32 x 80), 8x5 tiles, 3-term
//        split-bf16. Wave w owns d-tiles {2w, 2w+1}.
// y1 -> relu(+be1) -> split-bf16 -> LDS y1[i][d] (i = m+4, stride 136:
//        16B-aligned, 4-bank stride -> <=2-way = free).
// conv2 (G-trick): G[k'][i] = w2T(16x128) x Y1pad(128x96), 6 n-tiles over
//        wave w in {w, w+4}; then x[m] = sum_k G[k][m+k] (9 diagonal adds).
// 192 MFMA/row replaces ~3700 VALU FMA/lane of R7. LDS ~57.7 KB -> 2 blk/CU.
// ---------------------------------------------------------------------------
__global__ __launch_bounds__(256) void k_conv(
    const float* __restrict__ mel, const int* __restrict__ mel_len,
    const unsigned short* __restrict__ w1fh, const unsigned short* __restrict__ w1fl,
    const float* __restrict__ be1,
    const unsigned short* __restrict__ w2th, const unsigned short* __restrict__ w2tl,
    const float* __restrict__ g2, const float* __restrict__ be2,
    float* __restrict__ xout) {
    int b = blockIdx.y, t = blockIdx.x;
    if (t >= mel_len[b]) return;

    __shared__ __align__(16) unsigned short mh[96], mlo[96];
    __shared__ __align__(16) unsigned short y1h[96][136], y1l[96][136];
    __shared__ __align__(16) float gl[96][13];

    int tid = threadIdx.x, wave = tid >> 6, lane = tid & 63;
    int quad = lane >> 4, col = lane & 15;
    const float invs = 0.9999950000374997f;     // 1/sqrt(1+1e-5)

    // stage mel row (padded by 4) as split-bf16
    if (tid < 96) {
        float v = (tid >= 4 && tid < 84) ? mel[(b * TT + t) * NM + tid - 4] : 0.f;
        unsigned short hi = f2bf(v);
        mh[tid]  = hi;
        mlo[tid] = f2bf(v - __uint_as_float(((unsigned)hi) << 16));
    }
    // zero Y1pad halo rows {0..3, 84..95}
    for (int i = tid; i < 16 * 136; i += 256) {
        int r = i / 136, c2 = i - r * 136;
        int row = (r < 4) ? r : 80 + r;
        y1h[row][c2] = 0; y1l[row][c2] = 0;
    }
    __syncthreads();

    // ---- conv1 ----
    const short8* w1fh8 = (const short8*)w1fh;
    const short8* w1fl8 = (const short8*)w1fl;
    short8 a1h[2], a1l[2];
    float4 bb[2];
#pragma unroll
    for (int dd = 0; dd < 2; dd++) {
        int dt = 2 * wave + dd;
        a1h[dd] = w1fh8[dt * 64 + lane];
        a1l[dd] = w1fl8[dt * 64 + lane];
        bb[dd]  = *(const float4*)&be1[dt * 16 + quad * 4];
    }
#pragma unroll
    for (int nt = 0; nt < 5; nt++) {
        int mbase = nt * 16 + col;
        short8 Bh = {0,0,0,0,0,0,0,0}, Bl = {0,0,0,0,0,0,0,0};
        if (quad == 0) {            // k = 0..7
#pragma unroll
            for (int j = 0; j < 8; j++) {
                Bh[j] = (short)mh[mbase + j];
                Bl[j] = (short)mlo[mbase + j];
            }
        } else if (quad == 1) {     // k = 8 only (k=9..15 are zero-pad)
            Bh[0] = (short)mh[mbase + 8];
            Bl[0] = (short)mlo[mbase + 8];
        }
#pragma unroll
        for (int dd = 0; dd < 2; dd++) {
            f32x4 acc = (f32x4){0.f, 0.f, 0.f, 0.f};
            acc = __builtin_amdgcn_mfma_f32_16x16x32_bf16(a1h[dd], Bh, acc, 0, 0, 0);
            acc = __builtin_amdgcn_mfma_f32_16x16x32_bf16(a1h[dd], Bl, acc, 0, 0, 0);
            acc = __builtin_amdgcn_mfma_f32_16x16x32_bf16(a1l[dd], Bh, acc, 0, 0, 0);
            // C: row = d-in-tile = quad*4+reg, col = m (m89-verified layout)
            int i = mbase + 4;                      // Y1pad row (pad shift)
            int dbase = (2 * wave + dd) * 16 + quad * 4;
            float bbv[4] = {bb[dd].x, bb[dd].y, bb[dd].z, bb[dd].w};
            unsigned short hs4[4], ls4[4];
#pragma unroll
            for (int reg = 0; reg < 4; reg++) {
                float y = fmaxf(acc[reg] + bbv[reg], 0.f);
                unsigned short hi = f2bf(y);
                hs4[reg] = hi;
                ls4[reg] = f2bf(y - __uint_as_float(((unsigned)hi) << 16));
            }
            *(ushort4*)&y1h[i][dbase] = make_ushort4(hs4[0], hs4[1], hs4[2], hs4[3]);
            *(ushort4*)&y1l[i][dbase] = make_ushort4(ls4[0], ls4[1], ls4[2], ls4[3]);
        }
    }
    __syncthreads();

    // ---- conv2: G[k'][i] = W2^T x Y1pad ----
    const short8* w2th8 = (const short8*)w2th;
    const short8* w2tl8 = (const short8*)w2tl;
    short8 a2h[4], a2l[4];
#pragma unroll
    for (int k32 = 0; k32 < 4; k32++) {
        a2h[k32] = w2th8[k32 * 64 + lane];
        a2l[k32] = w2tl8[k32 * 64 + lane];
    }
    for (int nn = wave; nn < 6; nn += 4) {
        int i = nn * 16 + col;
        f32x4 acc = (f32x4){0.f, 0.f, 0.f, 0.f};
#pragma unroll
        for (int k32 = 0; k32 < 4; k32++) {
            short8 Bh = *(const short8*)&y1h[i][k32 * 32 + quad * 8];
            short8 Bl = *(const short8*)&y1l[i][k32 * 32 + quad * 8];
            acc = __builtin_amdgcn_mfma_f32_16x16x32_bf16(a2h[k32], Bh, acc, 0, 0, 0);
            acc = __builtin_amdgcn_mfma_f32_16x16x32_bf16(a2h[k32], Bl, acc, 0, 0, 0);
            acc = __builtin_amdgcn_mfma_f32_16x16x32_bf16(a2l[k32], Bh, acc, 0, 0, 0);
        }
#pragma unroll
        for (int reg = 0; reg < 4; reg++) {
            int kp = quad * 4 + reg;
            if (kp < KK) gl[i][kp] = acc[reg];
        }
    }
    __syncthreads();

    // ---- x[m] = sum_k G[k][m+k], BN2/ReLU, store ----
    if (tid < NM) {
        float s = 0.f;
#pragma unroll
        for (int k = 0; k < KK; k++) s += gl[tid + k][k];
        xout[(b * TT + t) * NM + tid] = fmaxf(0.f, fmaf(s, g2[0] * invs, be2[0]));
    }
}

// ---------------------------------------------------------------------------
// Kernel B: projection GEMM via split-bf16 MFMA (unchanged).
// ---------------------------------------------------------------------------
__global__ __launch_bounds__(256) void k_proj(
    const float* __restrict__ x,
    const unsigned short* __restrict__ wih_h, const unsigned short* __restrict__ wih_l,
    const float* __restrict__ biasc,
    float* __restrict__ xall) {
    __shared__ short8 bhs[2 * 3 * 64];
    __shared__ short8 bls[2 * 3 * 64];

    int tid = threadIdx.x;
    int wave = tid >> 6, lane = tid & 63, quad = lane >> 4;
    int row0 = blockIdx.x * 32;
    int tau0 = blockIdx.y * 24;

    for (int i = tid; i < 2 * 3 * 64; i += 256) {
        int rg = i / 192, rem = i - rg * 192;
        int ks = rem >> 6, ln = rem & 63;
        int row = row0 + rg * 16 + (ln & 15);
        int kb = ks * 32 + (ln >> 4) * 8;
        short8 hi8, lo8;
#pragma unroll
        for (int j = 0; j < 8; j++) {
            int k = kb + j;
            float v = (k < NM) ? x[row * NM + k] : 0.f;
            unsigned short hi = f2bf(v);
            float hif = __uint_as_float(((unsigned)hi) << 16);
            hi8[j] = (short)hi;
            lo8[j] = (short)f2bf(v - hif);
        }
        bhs[i] = hi8;
        bls[i] = lo8;
    }
    __syncthreads();

    const short8* wih_h8 = (const short8*)wih_h;
    const short8* wih_l8 = (const short8*)wih_l;

    for (int tt = 0; tt < 6; tt++) {
        int tau = tau0 + wave * 6 + tt;
        short8 Ah[3], Al[3];
#pragma unroll
        for (int ks = 0; ks < 3; ks++) {
            int ia = (tau * 3 + ks) * 64 + lane;
            Ah[ks] = wih_h8[ia];
            Al[ks] = wih_l8[ia];
        }
        f32x4 acc0 = (f32x4){0.f,0.f,0.f,0.f}, acc1 = (f32x4){0.f,0.f,0.f,0.f};
#pragma unroll
        for (int ks = 0; ks < 3; ks++) {
            short8 Bh0 = bhs[ks * 64 + lane],       Bl0 = bls[ks * 64 + lane];
            short8 Bh1 = bhs[192 + ks * 64 + lane], Bl1 = bls[192 + ks * 64 + lane];
            acc0 = __builtin_amdgcn_mfma_f32_16x16x32_bf16(Ah[ks], Bh0, acc0, 0, 0, 0);
            acc0 = __builtin_amdgcn_mfma_f32_16x16x32_bf16(Ah[ks], Bl0, acc0, 0, 0, 0);
            acc0 = __builtin_amdgcn_mfma_f32_16x16x32_bf16(Al[ks], Bh0, acc0, 0, 0, 0);
            acc1 = __builtin_amdgcn_mfma_f32_16x16x32_bf16(Ah[ks], Bh1, acc1, 0, 0, 0);
            acc1 = __builtin_amdgcn_mfma_f32_16x16x32_bf16(Ah[ks], Bl1, acc1, 0, 0, 0);
            acc1 = __builtin_amdgcn_mfma_f32_16x16x32_bf16(Al[ks], Bh1, acc1, 0, 0, 0);
        }
        float4 bias4 = *(const float4*)&biasc[tau * 16 + quad * 4];
        int ga = tau * 16 + quad * 4;
        int rowA = row0 + (lane & 15);
        float4 o0 = make_float4(acc0[0] + bias4.x, acc0[1] + bias4.y,
                                acc0[2] + bias4.z, acc0[3] + bias4.w);
        *(float4*)&xall[rowA * 768 + ga] = o0;
        int rowB = rowA + 16;
        float4 o1 = make_float4(acc1[0] + bias4.x, acc1[1] + bias4.y,
                                acc1[2] + bias4.z, acc1[3] + bias4.w);
        *(float4*)&xall[rowB * 768 + ga] = o1;
    }
}

// ---------------------------------------------------------------------------
// Kernel C: per-segment GRU, lane-local gate update (unchanged from R8).
// ---------------------------------------------------------------------------
__global__ __launch_bounds__(512) void k_gru(
    const float* __restrict__ xall,
    const unsigned short* __restrict__ wph, const unsigned short* __restrict__ wpl,
    const int* __restrict__ dur_all, const int* __restrict__ starts,
    const int* __restrict__ src_len,
    const float* __restrict__ bhf, const float* __restrict__ bhb,
    float* __restrict__ out) {
    int sblk = blockIdx.x;   // 0..6
    int b    = blockIdx.y;   // 0..7
    int dir  = blockIdx.z;   // 0 fwd, 1 bwd
    int s0 = sblk * 16;

    __shared__ __align__(16) unsigned short hbh[2][2048];   // ping-pong B-frag hi
    __shared__ __align__(16) unsigned short hbl[2][2048];   // ping-pong B-frag lo

    int tid  = threadIdx.x;
    int wave = tid >> 6, lane = tid & 63;
    int quad = lane >> 4, seg = lane & 15;

    for (int i = tid; i < 2048; i += 512) {
        hbh[0][i] = 0; hbl[0][i] = 0; hbh[1][i] = 0; hbl[1][i] = 0;
    }

    short8 Ah[3][4], Al[3][4];
    const short8* wph8 = (const short8*)wph;
    const short8* wpl8 = (const short8*)wpl;
#pragma unroll
    for (int tt = 0; tt < 3; tt++)
#pragma unroll
        for (int k32 = 0; k32 < 4; k32++) {
            int tau = wave + 8 * tt;
            int idx = ((dir * 24 + tau) * 4 + k32) * 64 + lane;
            Ah[tt][k32] = wph8[idx];
            Al[tt][k32] = wpl8[idx];
        }

    int s = s0 + seg;
    int sd = (s < SS) ? dur_all[b * SS + s] : 0;
    int st = (s < SS) ? starts[b * SS + s]  : 0;
    int slb = src_len[b];
    const float* bh = dir ? bhb : bhf;
    int j0 = wave * 16 + quad * 4;
    float4 bhr = *(const float4*)&bh[j0];
    float4 bhz = *(const float4*)&bh[DMC + j0];
    float4 bhn = *(const float4*)&bh[2 * DMC + j0];
    float4 h = make_float4(0.f, 0.f, 0.f, 0.f);

    int idx8 = (j0 >> 5) * 64 + ((j0 >> 3) & 3) * 16 + seg;
    int wbase = idx8 * 8 + (j0 & 7);

    __syncthreads();

    for (int i = 0; i < 12; i++) {
        int p = i & 1;
        bool act = (i < sd);

        float4 xr = make_float4(0.f,0.f,0.f,0.f), xz = xr, xn = xr;
        if (act) {
            int t = dir ? (st + sd - 1 - i) : (st + i);
            const float* xrow = xall + (size_t)(b * TT + t) * 768 + dir * G3 + j0;
            xr = *(const float4*)&xrow[0];
            xz = *(const float4*)&xrow[DMC];
            xn = *(const float4*)&xrow[2 * DMC];
        }

        f32x4 acc[3];
#pragma unroll
        for (int tt = 0; tt < 3; tt++) acc[tt] = (f32x4){0.f, 0.f, 0.f, 0.f};
#pragma unroll
        for (int k32 = 0; k32 < 4; k32++) {
            short8 Bh = ((const short8*)hbh[p])[k32 * 64 + lane];
            short8 Bl = ((const short8*)hbl[p])[k32 * 64 + lane];
#pragma unroll
            for (int tt = 0; tt < 3; tt++) {
                acc[tt] = __builtin_amdgcn_mfma_f32_16x16x32_bf16(Ah[tt][k32], Bh, acc[tt], 0, 0, 0);
                acc[tt] = __builtin_amdgcn_mfma_f32_16x16x32_bf16(Ah[tt][k32], Bl, acc[tt], 0, 0, 0);
                acc[tt] = __builtin_amdgcn_mfma_f32_16x16x32_bf16(Al[tt][k32], Bh, acc[tt], 0, 0, 0);
            }
        }

        if (act) {
            float hv[4] = {h.x, h.y, h.z, h.w};
            float xrv[4] = {xr.x, xr.y, xr.z, xr.w};
            float xzv[4] = {xz.x, xz.y, xz.z, xz.w};
            float xnv[4] = {xn.x, xn.y, xn.z, xn.w};
            float bhrv[4] = {bhr.x, bhr.y, bhr.z, bhr.w};
            float bhzv[4] = {bhz.x, bhz.y, bhz.z, bhz.w};
            float bhnv[4] = {bhn.x, bhn.y, bhn.z, bhn.w};
#pragma unroll
            for (int cmp = 0; cmp < 4; cmp++) {
                float r = sigmoid_(xrv[cmp] + acc[0][cmp] + bhrv[cmp]);
                float z = sigmoid_(xzv[cmp] + acc[1][cmp] + bhzv[cmp]);
                float n = tanh_(xnv[cmp] + r * (acc[2][cmp] + bhnv[cmp]));
                hv[cmp] = (1.f - z) * n + z * hv[cmp];
            }
            h = make_float4(hv[0], hv[1], hv[2], hv[3]);
            if (i == sd - 1) {
                float4 vout = (s < slb) ? h : make_float4(0.f, 0.f, 0.f, 0.f);
                *(float4*)&out[(b * SS + s) * (2 * DMC) + dir * DMC + j0] = vout;
            }
        }

        {
            float hv[4] = {h.x, h.y, h.z, h.w};
            unsigned short hs_[4], ls_[4];
#pragma unroll
            for (int cmp = 0; cmp < 4; cmp++) {
                unsigned short hi = f2bf(hv[cmp]);
                float hif = __uint_as_float(((unsigned)hi) << 16);
                hs_[cmp] = hi;
                ls_[cmp] = f2bf(hv[cmp] - hif);
            }
            *(ushort4*)&hbh[1 - p][wbase] = make_ushort4(hs_[0], hs_[1], hs_[2], hs_[3]);
            *(ushort4*)&hbl[1 - p][wbase] = make_ushort4(ls_[0], ls_[1], ls_[2], ls_[3]);
        }
        __syncthreads();
    }
}

// ---------------------------------------------------------------------------
extern "C" void kernel_launch(void* const* d_in, const int* in_sizes, int n_in,
                              void* d_out, int out_size, void* d_ws, size_t ws_size,
                              hipStream_t stream) {
    const float* mel      = (const float*)d_in[0];
    const int*   durations= (const int*)  d_in[1];
    const int*   mel_len  = (const int*)  d_in[2];
    const int*   src_len  = (const int*)  d_in[3];
    const float* w1       = (const float*)d_in[4];
    const float* g1       = (const float*)d_in[5];
    const float* be1      = (const float*)d_in[6];
    const float* w2       = (const float*)d_in[7];
    const float* g2       = (const float*)d_in[8];
    const float* be2      = (const float*)d_in[9];
    const float* w_ih_f   = (const float*)d_in[10];
    const float* w_hh_f   = (const float*)d_in[11];
    const float* b_ih_f   = (const float*)d_in[12];
    const float* b_hh_f   = (const float*)d_in[13];
    const float* w_ih_b   = (const float*)d_in[14];
    const float* w_hh_b   = (const float*)d_in[15];
    const float* b_ih_b   = (const float*)d_in[16];
    const float* b_hh_b   = (const float*)d_in[17];
    float* out = (float*)d_out;

    // workspace: x | xall | wph | wpl | wih_h | wih_l | biasc | starts | conv frags
    float* x    = (float*)d_ws;
    float* xall = x + NROW * NM;
    unsigned short* wph   = (unsigned short*)(xall + NROW * 768);
    unsigned short* wpl   = wph + 2 * 24 * 4 * 64 * 8;
    unsigned short* wih_h = wpl + 2 * 24 * 4 * 64 * 8;
    unsigned short* wih_l = wih_h + 48 * 3 * 64 * 8;
    float* biasc = (float*)(wih_l + 48 * 3 * 64 * 8);
    int*   starts= (int*)(biasc + 768);
    unsigned short* w1fh = (unsigned short*)(starts + 800);
    unsigned short* w1fl = w1fh + 512 * 8;
    unsigned short* w2th = w1fl + 512 * 8;
    unsigned short* w2tl = w2th + 256 * 8;

    k_prep<<<24, 1024, 0, stream>>>(w_hh_f, w_hh_b, w_ih_f, w_ih_b, b_ih_f, b_ih_b,
                                    durations, w1, g1, w2,
                                    wph, wpl, wih_h, wih_l, biasc, starts,
                                    w1fh, w1fl, w2th, w2tl);
    k_conv<<<dim3(TT, BB), 256, 0, stream>>>(mel, mel_len, w1fh, w1fl, be1,
                                             w2th, w2tl, g2, be2, x);
    k_proj<<<dim3(NROW / 32, 2), 256, 0, stream>>>(x, wih_h, wih_l, biasc, xall);
    k_gru<<<dim3(7, 8, 2), 512, 0, stream>>>(xall, wph, wpl, durations, starts, src_len,
                                             b_hh_f, b_hh_b, out);
}

// Round 10
// 166.863 us; speedup vs baseline: 1.1532x; 1.1532x over previous
//
#include <hip/hip_runtime.h>
#include <math.h>

// Problem constants
#define BB   8
#define SS   100
#define TT   1200        // S * DMAX
#define NM   80          // NMEL
#define DMC  128         // DM
#define KK   9
#define G3   384         // 3*DM
#define NROW (BB*TT)     // 9600

typedef __attribute__((ext_vector_type(8))) short short8;
typedef __attribute__((ext_vector_type(4))) float f32x4;

__device__ __forceinline__ float sigmoid_(float v) { return 1.f / (1.f + __expf(-v)); }
__device__ __forceinline__ float tanh_(float v) {
    float a = fabsf(v);
    float e = __expf(-2.f * a);
    float t = (1.f - e) / (1.f + e);
    return copysignf(t, v);
}
__device__ __forceinline__ unsigned short f2bf(float f) {   // RNE fp32->bf16
    unsigned int u = __float_as_uint(f);
    unsigned int r = (u + 0x7fffu + ((u >> 16) & 1u)) >> 16;
    return (unsigned short)r;
}

// ---------------------------------------------------------------------------
// Kernel P (fused prep), 22 blocks x 1024 thr:
//   blk 0..11  : pack w_hh into A-frag split-bf16
//   blk 12..20 : pack w_ih into A-frag split-bf16 (K=80 pad 96)
//   blk 21     : durations prefix-scan -> starts; concat b_ih biases
// A-frag (16x16x32 bf16): lane holds A[m=lane&15][k=(lane>>4)*8 + j], j=0..7
// ---------------------------------------------------------------------------
__global__ __launch_bounds__(1024) void k_prep(
    const float* __restrict__ whf, const float* __restrict__ whb,
    const float* __restrict__ wif, const float* __restrict__ wib,
    const float* __restrict__ bf, const float* __restrict__ bbv,
    const int* __restrict__ dur,
    unsigned short* __restrict__ wph, unsigned short* __restrict__ wpl,
    unsigned short* __restrict__ wih_h, unsigned short* __restrict__ wih_l,
    float* __restrict__ biasc, int* __restrict__ starts) {
    int blk = blockIdx.x;
    int tid = threadIdx.x;
    if (blk < 12) {
        int idx = blk * 1024 + tid;           // [0, 12288)
        int lane = idx & 63;
        int k32  = (idx >> 6) & 3;
        int tau  = (idx >> 8) % 24;
        int dir  = idx / (24 * 4 * 64);
        const float* w = dir ? whb : whf;
        int g = tau * 16 + (lane & 15);
        int kbase = k32 * 32 + (lane >> 4) * 8;
#pragma unroll
        for (int j = 0; j < 8; j++) {
            float v = w[g * DMC + kbase + j];
            unsigned short hi = f2bf(v);
            float hif = __uint_as_float(((unsigned)hi) << 16);
            unsigned short lo = f2bf(v - hif);
            wph[idx * 8 + j] = hi;
            wpl[idx * 8 + j] = lo;
        }
    } else if (blk < 21) {
        int idx = (blk - 12) * 1024 + tid;    // [0, 9216)
        int lane = idx & 63;
        int ks   = (idx >> 6) % 3;
        int tau  = idx / (3 * 64);            // 0..47 ; dir = tau>=24
        int gate = tau * 16 + (lane & 15);
        int kb   = ks * 32 + (lane >> 4) * 8;
        const float* w = (gate < G3) ? (wif + gate * NM) : (wib + (gate - G3) * NM);
#pragma unroll
        for (int j = 0; j < 8; j++) {
            int k = kb + j;
            float v = (k < NM) ? w[k] : 0.f;
            unsigned short hi = f2bf(v);
            float hif = __uint_as_float(((unsigned)hi) << 16);
            unsigned short lo = f2bf(v - hif);
            wih_h[idx * 8 + j] = hi;
            wih_l[idx * 8 + j] = lo;
        }
    } else {
        __shared__ int buf[BB][128];
        int s = tid & 127, b = tid >> 7;
        int v = (s < SS) ? dur[b * SS + s] : 0;
        buf[b][s] = v;
        __syncthreads();
        for (int off = 1; off < 128; off <<= 1) {
            int t = (s >= off) ? buf[b][s - off] : 0;
            __syncthreads();
            buf[b][s] += t;
            __syncthreads();
        }
        if (s < SS) starts[b * SS + s] = buf[b][s] - v;
        if (tid < 768) biasc[tid] = (tid < G3) ? bf[tid] : bbv[tid - G3];
    }
}

// ---------------------------------------------------------------------------
// Kernel A: fused conv1+BN/ReLU+conv2+BN/ReLU — register-resident, SPILL-FREE
// (reverted to the proven R7 version: VGPR 52, ~51 us, VALUBusy 78%).
// ---------------------------------------------------------------------------
__global__ __launch_bounds__(256) void k_conv(
    const float* __restrict__ mel, const int* __restrict__ mel_len,
    const float* __restrict__ w1, const float* __restrict__ g1, const float* __restrict__ be1,
    const float* __restrict__ w2, const float* __restrict__ g2, const float* __restrict__ be2,
    float* __restrict__ xout) {
    int b = blockIdx.y;
    int t = blockIdx.x;
    int ml = mel_len[b];
    if (t >= ml) return;

    __shared__ __align__(16) float mp[96];          // mp[i] = mel[i-8], i in [8,88)
    __shared__ __align__(16) float part[8][84];     // octet partials

    int tid = threadIdx.x;
    int mq = tid >> 6, g = tid & 63;
    int ms = 20 * mq;
    const float inv_sqrt = 0.9999950000374997f;     // 1/sqrt(1+1e-5)

    if (tid < 96) {
        float v = 0.f;
        if (tid >= 8 && tid < 88) v = mel[(b * TT + t) * NM + tid - 8];
        mp[tid] = v;
    }
    __syncthreads();

    float c[20];
#pragma unroll
    for (int m = 0; m < 20; m++) c[m] = 0.f;

#pragma unroll 1
    for (int dd = 0; dd < 2; dd++) {
        int d = g + 64 * dd;
        float sc = g1[d] * inv_sqrt;
        float w1r[KK], w2r[KK];
#pragma unroll
        for (int k = 0; k < KK; k++) { w1r[k] = w1[d * KK + k] * sc; w2r[k] = w2[d * KK + k]; }
        float sb = be1[d];

        float mw[12];
        {
            const float4* p4 = (const float4*)(mp + ms);
            float4 a = p4[0], bq = p4[1], cq = p4[2];
            mw[0]=a.x;  mw[1]=a.y;  mw[2]=a.z;  mw[3]=a.w;
            mw[4]=bq.x; mw[5]=bq.y; mw[6]=bq.z; mw[7]=bq.w;
            mw[8]=cq.x; mw[9]=cq.y; mw[10]=cq.z; mw[11]=cq.w;
        }
#pragma unroll
        for (int ch = 0; ch < 7; ch++) {
#pragma unroll
            for (int jj = 0; jj < 4; jj++) {
                int off = ch * 4 + jj;
                float yv = sb;
#pragma unroll
                for (int k = 0; k < KK; k++) yv = fmaf(w1r[k], mw[jj + k], yv);
                yv = fmaxf(yv, 0.f);
                int j = ms + off;
                if (j < 4 || j >= 84) yv = 0.f;
#pragma unroll
                for (int k = 0; k < KK; k++) {
                    int mo = off - k;
                    if (mo >= 0 && mo < 20) c[mo] = fmaf(w2r[k], yv, c[mo]);
                }
            }
            if (ch < 6) {
#pragma unroll
                for (int q = 0; q < 8; q++) mw[q] = mw[q + 4];
                const float4* p4 = (const float4*)(mp + ms + ch * 4 + 12);
                float4 a = p4[0];
                mw[8]=a.x; mw[9]=a.y; mw[10]=a.z; mw[11]=a.w;
            }
        }
    }

#pragma unroll
    for (int m = 0; m < 20; m++) {
        c[m] += __shfl_xor(c[m], 1);
        c[m] += __shfl_xor(c[m], 2);
        c[m] += __shfl_xor(c[m], 4);
    }
    if ((g & 7) == 0) {
        int p = g >> 3;
#pragma unroll
        for (int m = 0; m < 20; m += 4)
            *(float4*)&part[p][ms + m] = make_float4(c[m], c[m+1], c[m+2], c[m+3]);
    }
    __syncthreads();

    if (tid < 80) {
        float s = 0.f;
#pragma unroll
        for (int p = 0; p < 8; p++) s += part[p][tid];
        float v = fmaxf(0.f, fmaf(s, g2[0] * inv_sqrt, be2[0]));
        xout[(b * TT + t) * NM + tid] = v;
    }
}

// ---------------------------------------------------------------------------
// Kernel C (R10): FUSED projection + GRU. xall is never materialized.
// 512 thr = 8 waves, grid (7,8,2). Wave w owns tau tiles {w, w+8, w+16}.
// Per iter: x rows for the 16 current segment-steps staged into split-bf16
// B-frags (ping-pong); MFMA accumulates x.w_ih AND h.w_hh:
//   acc0 = r-sum (fused), acc1 = z-sum (fused), acc2 = hn (h only),
//   acc3 = xn (x only)   [n-gate is NOT additive: tanh(xn + r*hn)]
// w_hh and w_ih A-frags persist in the unified VGPR/AGPR file.
// __launch_bounds__(512,2): 2 waves/EU -> 256-VGPR budget, no spill.
// ---------------------------------------------------------------------------
__global__ __launch_bounds__(512, 2) void k_gru(
    const float* __restrict__ x,
    const unsigned short* __restrict__ wph, const unsigned short* __restrict__ wpl,
    const unsigned short* __restrict__ wih_h, const unsigned short* __restrict__ wih_l,
    const float* __restrict__ biasc,
    const int* __restrict__ dur_all, const int* __restrict__ starts,
    const int* __restrict__ src_len,
    const float* __restrict__ bhf, const float* __restrict__ bhb,
    float* __restrict__ out) {
    int sblk = blockIdx.x;   // 0..6
    int b    = blockIdx.y;   // 0..7
    int dir  = blockIdx.z;   // 0 fwd, 1 bwd
    int s0 = sblk * 16;

    __shared__ __align__(16) unsigned short hbh[2][2048];   // h B-frags hi (pp)
    __shared__ __align__(16) unsigned short hbl[2][2048];   // h B-frags lo (pp)
    __shared__ __align__(16) short8 xbh[2][192];            // x B-frags hi (pp)
    __shared__ __align__(16) short8 xbl[2][192];            // x B-frags lo (pp)
    __shared__ int sdur[16], sstart[16];

    int tid  = threadIdx.x;
    int wave = tid >> 6, lane = tid & 63;
    int quad = lane >> 4, seg = lane & 15;

    if (tid < 16) {
        int ss = s0 + tid;
        sdur[tid]   = (ss < SS) ? dur_all[b * SS + ss] : 0;
        sstart[tid] = (ss < SS) ? starts[b * SS + ss]  : 0;
    }
    for (int i = tid; i < 2048; i += 512) { hbh[0][i] = 0; hbl[0][i] = 0; }

    // ---- w_hh A-frags (taus wave, wave+8, wave+16), persist in regs ----
    short8 Ah[3][4], Al[3][4];
    const short8* wph8 = (const short8*)wph;
    const short8* wpl8 = (const short8*)wpl;
#pragma unroll
    for (int tt = 0; tt < 3; tt++)
#pragma unroll
        for (int k32 = 0; k32 < 4; k32++) {
            int idx = ((dir * 24 + wave + 8 * tt) * 4 + k32) * 64 + lane;
            Ah[tt][k32] = wph8[idx];
            Al[tt][k32] = wpl8[idx];
        }
    // ---- w_ih A-frags (same taus, K=96), persist in regs ----
    short8 Gh[3][3], Gl[3][3];
    const short8* wih_h8 = (const short8*)wih_h;
    const short8* wih_l8 = (const short8*)wih_l;
#pragma unroll
    for (int tt = 0; tt < 3; tt++)
#pragma unroll
        for (int ks = 0; ks < 3; ks++) {
            int idx = ((dir * 24 + wave + 8 * tt) * 3 + ks) * 64 + lane;
            Gh[tt][ks] = wih_h8[idx];
            Gl[tt][ks] = wih_l8[idx];
        }

    // ---- per-lane meta & biases ----
    int s = s0 + seg;
    int sd = (s < SS) ? dur_all[b * SS + s] : 0;
    int st = (s < SS) ? starts[b * SS + s]  : 0;
    int slb = src_len[b];
    const float* bih = biasc + dir * G3;
    const float* bhh = dir ? bhb : bhf;
    int j0 = wave * 16 + quad * 4;
    float4 i_r = *(const float4*)&bih[j0];
    float4 i_z = *(const float4*)&bih[DMC + j0];
    float4 bxn = *(const float4*)&bih[2 * DMC + j0];
    float4 h_r = *(const float4*)&bhh[j0];
    float4 h_z = *(const float4*)&bhh[DMC + j0];
    float4 bhn = *(const float4*)&bhh[2 * DMC + j0];
    float4 br = make_float4(i_r.x + h_r.x, i_r.y + h_r.y, i_r.z + h_r.z, i_r.w + h_r.w);
    float4 bz = make_float4(i_z.x + h_z.x, i_z.y + h_z.y, i_z.z + h_z.z, i_z.w + h_z.w);
    float4 h = make_float4(0.f, 0.f, 0.f, 0.f);

    int idx8 = (j0 >> 5) * 64 + ((j0 >> 3) & 3) * 16 + seg;
    int wbase = idx8 * 8 + (j0 & 7);             // h-frag write addr (shorts)

    __syncthreads();   // sdur/sstart + h[0] visible

    // ---- stage x B-frags for iter 0 into buffer 0 ----
    if (tid < 192) {
        int ks = tid >> 6, ln = tid & 63;
        int sg = ln & 15, qq = ln >> 4;
        int kb = ks * 32 + qq * 8;
        short8 hi8 = {0,0,0,0,0,0,0,0}, lo8 = {0,0,0,0,0,0,0,0};
        if (kb < NM && 0 < sdur[sg]) {
            int t = dir ? (sstart[sg] + sdur[sg] - 1) : sstart[sg];
            const float* xr = x + (size_t)(b * TT + t) * NM + kb;
#pragma unroll
            for (int j = 0; j < 8; j++) {
                float v = xr[j];
                unsigned short hi = f2bf(v);
                hi8[j] = (short)hi;
                lo8[j] = (short)f2bf(v - __uint_as_float(((unsigned)hi) << 16));
            }
        }
        xbh[0][tid] = hi8;
        xbl[0][tid] = lo8;
    }
    __syncthreads();

    for (int i = 0; i < 12; i++) {
        int p = i & 1;
        bool act = (i < sd);

        // ---- MFMA: 27 x-part + 36 h-part, split-bf16 3-term each ----
        f32x4 acc0 = (f32x4){0.f,0.f,0.f,0.f};   // r fused
        f32x4 acc1 = (f32x4){0.f,0.f,0.f,0.f};   // z fused
        f32x4 acc2 = (f32x4){0.f,0.f,0.f,0.f};   // hn
        f32x4 acc3 = (f32x4){0.f,0.f,0.f,0.f};   // xn
#pragma unroll
        for (int ks = 0; ks < 3; ks++) {
            short8 Bxh = xbh[p][ks * 64 + lane];
            short8 Bxl = xbl[p][ks * 64 + lane];
            acc0 = __builtin_amdgcn_mfma_f32_16x16x32_bf16(Gh[0][ks], Bxh, acc0, 0, 0, 0);
            acc0 = __builtin_amdgcn_mfma_f32_16x16x32_bf16(Gh[0][ks], Bxl, acc0, 0, 0, 0);
            acc0 = __builtin_amdgcn_mfma_f32_16x16x32_bf16(Gl[0][ks], Bxh, acc0, 0, 0, 0);
            acc1 = __builtin_amdgcn_mfma_f32_16x16x32_bf16(Gh[1][ks], Bxh, acc1, 0, 0, 0);
            acc1 = __builtin_amdgcn_mfma_f32_16x16x32_bf16(Gh[1][ks], Bxl, acc1, 0, 0, 0);
            acc1 = __builtin_amdgcn_mfma_f32_16x16x32_bf16(Gl[1][ks], Bxh, acc1, 0, 0, 0);
            acc3 = __builtin_amdgcn_mfma_f32_16x16x32_bf16(Gh[2][ks], Bxh, acc3, 0, 0, 0);
            acc3 = __builtin_amdgcn_mfma_f32_16x16x32_bf16(Gh[2][ks], Bxl, acc3, 0, 0, 0);
            acc3 = __builtin_amdgcn_mfma_f32_16x16x32_bf16(Gl[2][ks], Bxh, acc3, 0, 0, 0);
        }
#pragma unroll
        for (int k32 = 0; k32 < 4; k32++) {
            short8 Bh = ((const short8*)hbh[p])[k32 * 64 + lane];
            short8 Bl = ((const short8*)hbl[p])[k32 * 64 + lane];
            acc0 = __builtin_amdgcn_mfma_f32_16x16x32_bf16(Ah[0][k32], Bh, acc0, 0, 0, 0);
            acc0 = __builtin_amdgcn_mfma_f32_16x16x32_bf16(Ah[0][k32], Bl, acc0, 0, 0, 0);
            acc0 = __builtin_amdgcn_mfma_f32_16x16x32_bf16(Al[0][k32], Bh, acc0, 0, 0, 0);
            acc1 = __builtin_amdgcn_mfma_f32_16x16x32_bf16(Ah[1][k32], Bh, acc1, 0, 0, 0);
            acc1 = __builtin_amdgcn_mfma_f32_16x16x32_bf16(Ah[1][k32], Bl, acc1, 0, 0, 0);
            acc1 = __builtin_amdgcn_mfma_f32_16x16x32_bf16(Al[1][k32], Bh, acc1, 0, 0, 0);
            acc2 = __builtin_amdgcn_mfma_f32_16x16x32_bf16(Ah[2][k32], Bh, acc2, 0, 0, 0);
            acc2 = __builtin_amdgcn_mfma_f32_16x16x32_bf16(Ah[2][k32], Bl, acc2, 0, 0, 0);
            acc2 = __builtin_amdgcn_mfma_f32_16x16x32_bf16(Al[2][k32], Bh, acc2, 0, 0, 0);
        }

        // ---- lane-local GRU update ----
        if (act) {
            float hv[4]  = {h.x, h.y, h.z, h.w};
            float brv[4] = {br.x, br.y, br.z, br.w};
            float bzv[4] = {bz.x, bz.y, bz.z, bz.w};
            float bxv[4] = {bxn.x, bxn.y, bxn.z, bxn.w};
            float bhv[4] = {bhn.x, bhn.y, bhn.z, bhn.w};
#pragma unroll
            for (int cmp = 0; cmp < 4; cmp++) {
                float r = sigmoid_(acc0[cmp] + brv[cmp]);
                float z = sigmoid_(acc1[cmp] + bzv[cmp]);
                float n = tanh_(acc3[cmp] + bxv[cmp] + r * (acc2[cmp] + bhv[cmp]));
                hv[cmp] = (1.f - z) * n + z * hv[cmp];
            }
            h = make_float4(hv[0], hv[1], hv[2], hv[3]);
            if (i == sd - 1) {
                float4 vout = (s < slb) ? h : make_float4(0.f, 0.f, 0.f, 0.f);
                *(float4*)&out[(b * SS + s) * (2 * DMC) + dir * DMC + j0] = vout;
            }
        }

        // ---- write h frags (split-bf16) to the other buffer ----
        {
            float hv[4] = {h.x, h.y, h.z, h.w};
            unsigned short hs_[4], ls_[4];
#pragma unroll
            for (int cmp = 0; cmp < 4; cmp++) {
                unsigned short hi = f2bf(hv[cmp]);
                float hif = __uint_as_float(((unsigned)hi) << 16);
                hs_[cmp] = hi;
                ls_[cmp] = f2bf(hv[cmp] - hif);
            }
            *(ushort4*)&hbh[1 - p][wbase] = make_ushort4(hs_[0], hs_[1], hs_[2], hs_[3]);
            *(ushort4*)&hbl[1 - p][wbase] = make_ushort4(ls_[0], ls_[1], ls_[2], ls_[3]);
        }

        // ---- stage x B-frags for iter i+1 into the other buffer ----
        if (tid < 192) {
            int i2 = i + 1;
            int ks = tid >> 6, ln = tid & 63;
            int sg = ln & 15, qq = ln >> 4;
            int kb = ks * 32 + qq * 8;
            short8 hi8 = {0,0,0,0,0,0,0,0}, lo8 = {0,0,0,0,0,0,0,0};
            int d2 = sdur[sg];
            if (kb < NM && i2 < d2) {
                int t = dir ? (sstart[sg] + d2 - 1 - i2) : (sstart[sg] + i2);
                const float* xr = x + (size_t)(b * TT + t) * NM + kb;
#pragma unroll
                for (int j = 0; j < 8; j++) {
                    float v = xr[j];
                    unsigned short hi = f2bf(v);
                    hi8[j] = (short)hi;
                    lo8[j] = (short)f2bf(v - __uint_as_float(((unsigned)hi) << 16));
                }
            }
            xbh[1 - p][tid] = hi8;
            xbl[1 - p][tid] = lo8;
        }
        __syncthreads();
    }
}

// ---------------------------------------------------------------------------
extern "C" void kernel_launch(void* const* d_in, const int* in_sizes, int n_in,
                              void* d_out, int out_size, void* d_ws, size_t ws_size,
                              hipStream_t stream) {
    const float* mel      = (const float*)d_in[0];
    const int*   durations= (const int*)  d_in[1];
    const int*   mel_len  = (const int*)  d_in[2];
    const int*   src_len  = (const int*)  d_in[3];
    const float* w1       = (const float*)d_in[4];
    const float* g1       = (const float*)d_in[5];
    const float* be1      = (const float*)d_in[6];
    const float* w2       = (const float*)d_in[7];
    const float* g2       = (const float*)d_in[8];
    const float* be2      = (const float*)d_in[9];
    const float* w_ih_f   = (const float*)d_in[10];
    const float* w_hh_f   = (const float*)d_in[11];
    const float* b_ih_f   = (const float*)d_in[12];
    const float* b_hh_f   = (const float*)d_in[13];
    const float* w_ih_b   = (const float*)d_in[14];
    const float* w_hh_b   = (const float*)d_in[15];
    const float* b_ih_b   = (const float*)d_in[16];
    const float* b_hh_b   = (const float*)d_in[17];
    float* out = (float*)d_out;

    // workspace: x | wph | wpl | wih_h | wih_l | biasc | starts  (xall GONE)
    float* x    = (float*)d_ws;
    unsigned short* wph   = (unsigned short*)(x + NROW * NM);
    unsigned short* wpl   = wph + 2 * 24 * 4 * 64 * 8;
    unsigned short* wih_h = wpl + 2 * 24 * 4 * 64 * 8;
    unsigned short* wih_l = wih_h + 48 * 3 * 64 * 8;
    float* biasc = (float*)(wih_l + 48 * 3 * 64 * 8);
    int*   starts= (int*)(biasc + 768);

    k_prep<<<22, 1024, 0, stream>>>(w_hh_f, w_hh_b, w_ih_f, w_ih_b, b_ih_f, b_ih_b,
                                    durations, wph, wpl, wih_h, wih_l, biasc, starts);
    k_conv<<<dim3(TT, BB), 256, 0, stream>>>(mel, mel_len, w1, g1, be1, w2, g2, be2, x);
    k_gru<<<dim3(7, 8, 2), 512, 0, stream>>>(x, wph, wpl, wih_h, wih_l, biasc,
                                             durations, starts, src_len,
                                             b_hh_f, b_hh_b, out);
}

// Round 11
// 165.778 us; speedup vs baseline: 1.1607x; 1.0065x over previous
//
#include <hip/hip_runtime.h>
#include <math.h>

// Problem constants
#define BB   8
#define SS   100
#define TT   1200        // S * DMAX
#define NM   80          // NMEL
#define DMC  128         // DM
#define KK   9
#define G3   384         // 3*DM
#define NROW (BB*TT)     // 9600

typedef __attribute__((ext_vector_type(8))) short short8;
typedef __attribute__((ext_vector_type(4))) float f32x4;
typedef __attribute__((ext_vector_type(2))) float f32x2;

__device__ __forceinline__ float sigmoid_(float v) { return 1.f / (1.f + __expf(-v)); }
__device__ __forceinline__ float tanh_(float v) {
    float a = fabsf(v);
    float e = __expf(-2.f * a);
    float t = (1.f - e) / (1.f + e);
    return copysignf(t, v);
}
__device__ __forceinline__ unsigned short f2bf(float f) {   // RNE fp32->bf16
    unsigned int u = __float_as_uint(f);
    unsigned int r = (u + 0x7fffu + ((u >> 16) & 1u)) >> 16;
    return (unsigned short)r;
}
// CDNA packed fp32 FMA: d = a*b + c per 32-bit half (VOP3P v_pk_fma_f32)
__device__ __forceinline__ f32x2 pk_fma(f32x2 a, f32x2 b, f32x2 c) {
    f32x2 d;
    asm("v_pk_fma_f32 %0, %1, %2, %3" : "=v"(d) : "v"(a), "v"(b), "v"(c));
    return d;
}

// ---------------------------------------------------------------------------
// Kernel P (fused prep), 22 blocks x 1024 thr (unchanged from R10).
// ---------------------------------------------------------------------------
__global__ __launch_bounds__(1024) void k_prep(
    const float* __restrict__ whf, const float* __restrict__ whb,
    const float* __restrict__ wif, const float* __restrict__ wib,
    const float* __restrict__ bf, const float* __restrict__ bbv,
    const int* __restrict__ dur,
    unsigned short* __restrict__ wph, unsigned short* __restrict__ wpl,
    unsigned short* __restrict__ wih_h, unsigned short* __restrict__ wih_l,
    float* __restrict__ biasc, int* __restrict__ starts) {
    int blk = blockIdx.x;
    int tid = threadIdx.x;
    if (blk < 12) {
        int idx = blk * 1024 + tid;           // [0, 12288)
        int lane = idx & 63;
        int k32  = (idx >> 6) & 3;
        int tau  = (idx >> 8) % 24;
        int dir  = idx / (24 * 4 * 64);
        const float* w = dir ? whb : whf;
        int g = tau * 16 + (lane & 15);
        int kbase = k32 * 32 + (lane >> 4) * 8;
#pragma unroll
        for (int j = 0; j < 8; j++) {
            float v = w[g * DMC + kbase + j];
            unsigned short hi = f2bf(v);
            float hif = __uint_as_float(((unsigned)hi) << 16);
            unsigned short lo = f2bf(v - hif);
            wph[idx * 8 + j] = hi;
            wpl[idx * 8 + j] = lo;
        }
    } else if (blk < 21) {
        int idx = (blk - 12) * 1024 + tid;    // [0, 9216)
        int lane = idx & 63;
        int ks   = (idx >> 6) % 3;
        int tau  = idx / (3 * 64);            // 0..47 ; dir = tau>=24
        int gate = tau * 16 + (lane & 15);
        int kb   = ks * 32 + (lane >> 4) * 8;
        const float* w = (gate < G3) ? (wif + gate * NM) : (wib + (gate - G3) * NM);
#pragma unroll
        for (int j = 0; j < 8; j++) {
            int k = kb + j;
            float v = (k < NM) ? w[k] : 0.f;
            unsigned short hi = f2bf(v);
            float hif = __uint_as_float(((unsigned)hi) << 16);
            unsigned short lo = f2bf(v - hif);
            wih_h[idx * 8 + j] = hi;
            wih_l[idx * 8 + j] = lo;
        }
    } else {
        __shared__ int buf[BB][128];
        int s = tid & 127, b = tid >> 7;
        int v = (s < SS) ? dur[b * SS + s] : 0;
        buf[b][s] = v;
        __syncthreads();
        for (int off = 1; off < 128; off <<= 1) {
            int t = (s >= off) ? buf[b][s - off] : 0;
            __syncthreads();
            buf[b][s] += t;
            __syncthreads();
        }
        if (s < SS) starts[b * SS + s] = buf[b][s] - v;
        if (tid < 768) biasc[tid] = (tid < G3) ? bf[tid] : bbv[tid - G3];
    }
}

// ---------------------------------------------------------------------------
// Kernel A (R11): conv1+BN/ReLU+conv2+BN/ReLU, TWO rows per block packed
// into f32x2 lanes and computed with v_pk_fma_f32 (packed fp32). Same
// per-row math/order as R7 (bit-identical output); per-row inst count
// halves if pk is full-rate, staging/slide/reduce amortize 2x regardless.
// ---------------------------------------------------------------------------
__global__ __launch_bounds__(256) void k_conv(
    const float* __restrict__ mel, const int* __restrict__ mel_len,
    const float* __restrict__ w1, const float* __restrict__ g1, const float* __restrict__ be1,
    const float* __restrict__ w2, const float* __restrict__ g2, const float* __restrict__ be2,
    float* __restrict__ xout) {
    int b  = blockIdx.y;
    int t0 = blockIdx.x * 2;
    int ml = mel_len[b];
    if (t0 >= ml) return;

    __shared__ __align__(16) f32x2 mp2[96];         // mp2[i] = {row0, row1}[i-8]
    __shared__ __align__(16) f32x2 part2[8][82];    // octet partials (pair rows)

    int tid = threadIdx.x;
    int mq = tid >> 6, g = tid & 63;
    int ms = 20 * mq;
    const float inv_sqrt = 0.9999950000374997f;     // 1/sqrt(1+1e-5)

    if (tid < 192) {
        int rr = tid / 96, i = tid - rr * 96;
        float v = 0.f;
        if (i >= 8 && i < 88) v = mel[(b * TT + t0 + rr) * NM + i - 8];
        ((float*)mp2)[i * 2 + rr] = v;
    }
    __syncthreads();

    f32x2 c[20];
#pragma unroll
    for (int m = 0; m < 20; m++) c[m] = (f32x2){0.f, 0.f};

#pragma unroll 1
    for (int dd = 0; dd < 2; dd++) {
        int d = g + 64 * dd;
        float sc = g1[d] * inv_sqrt;
        f32x2 w1p[KK], w2p[KK];
#pragma unroll
        for (int k = 0; k < KK; k++) {
            float a = w1[d * KK + k] * sc;
            float bq = w2[d * KK + k];
            w1p[k] = (f32x2){a, a};
            w2p[k] = (f32x2){bq, bq};
        }
        float sb = be1[d];

        f32x2 mw[12];   // sliding window (pair of rows per element)
        {
            const float4* p4 = (const float4*)(mp2 + ms);
#pragma unroll
            for (int q = 0; q < 6; q++) {
                float4 v = p4[q];
                mw[2 * q]     = (f32x2){v.x, v.y};
                mw[2 * q + 1] = (f32x2){v.z, v.w};
            }
        }
#pragma unroll
        for (int ch = 0; ch < 7; ch++) {
#pragma unroll
            for (int jj = 0; jj < 4; jj++) {
                int off = ch * 4 + jj;
                f32x2 yv = (f32x2){sb, sb};
#pragma unroll
                for (int k = 0; k < KK; k++) yv = pk_fma(w1p[k], mw[jj + k], yv);
                yv[0] = fmaxf(yv[0], 0.f);
                yv[1] = fmaxf(yv[1], 0.f);
                int j = ms + off;
                if (j < 4 || j >= 84) yv = (f32x2){0.f, 0.f};   // conv1 halo (static)
#pragma unroll
                for (int k = 0; k < KK; k++) {
                    int mo = off - k;
                    if (mo >= 0 && mo < 20) c[mo] = pk_fma(w2p[k], yv, c[mo]);
                }
            }
            if (ch < 6) {   // slide window by 4
#pragma unroll
                for (int q = 0; q < 8; q++) mw[q] = mw[q + 4];
                const float4* p4 = (const float4*)(mp2 + ms + ch * 4 + 12);
                float4 a0 = p4[0], a1 = p4[1];
                mw[8]  = (f32x2){a0.x, a0.y};
                mw[9]  = (f32x2){a0.z, a0.w};
                mw[10] = (f32x2){a1.x, a1.y};
                mw[11] = (f32x2){a1.z, a1.w};
            }
        }
    }

    // ---- butterfly reduce over g within octets (both rows) ----
#pragma unroll
    for (int m = 0; m < 20; m++) {
        c[m][0] += __shfl_xor(c[m][0], 1);
        c[m][1] += __shfl_xor(c[m][1], 1);
        c[m][0] += __shfl_xor(c[m][0], 2);
        c[m][1] += __shfl_xor(c[m][1], 2);
        c[m][0] += __shfl_xor(c[m][0], 4);
        c[m][1] += __shfl_xor(c[m][1], 4);
    }
    if ((g & 7) == 0) {
        int p = g >> 3;
#pragma unroll
        for (int m = 0; m < 20; m++) part2[p][ms + m] = c[m];
    }
    __syncthreads();

    // ---- final: sum 8 octet partials + BN2/ReLU + store (2 rows) ----
    if (tid < 160) {
        int rr = (tid >= 80) ? 1 : 0;
        int m  = tid - 80 * rr;
        int t  = t0 + rr;
        if (t < ml) {
            float s = 0.f;
#pragma unroll
            for (int p = 0; p < 8; p++) s += part2[p][m][rr];
            float v = fmaxf(0.f, fmaf(s, g2[0] * inv_sqrt, be2[0]));
            xout[(b * TT + t) * NM + m] = v;
        }
    }
}

// ---------------------------------------------------------------------------
// Kernel C (R11): fused projection+GRU; ALL 12 iterations of x B-frags are
// pre-staged into LDS once (t depends only on i) with 5 unrolled in-flight
// loads -> no per-iteration exposed HBM latency. x/h accumulator chains
// split (6 chains <=12 deep instead of 4 of 21). One barrier per iter.
// LDS ~90 KB -> 1 block/CU (grid is 112 blocks anyway).
// ---------------------------------------------------------------------------
__global__ __launch_bounds__(512, 2) void k_gru(
    const float* __restrict__ x,
    const unsigned short* __restrict__ wph, const unsigned short* __restrict__ wpl,
    const unsigned short* __restrict__ wih_h, const unsigned short* __restrict__ wih_l,
    const float* __restrict__ biasc,
    const int* __restrict__ dur_all, const int* __restrict__ starts,
    const int* __restrict__ src_len,
    const float* __restrict__ bhf, const float* __restrict__ bhb,
    float* __restrict__ out) {
    int sblk = blockIdx.x;   // 0..6
    int b    = blockIdx.y;   // 0..7
    int dir  = blockIdx.z;   // 0 fwd, 1 bwd
    int s0 = sblk * 16;

    __shared__ __align__(16) short8 xbh[12][192];           // x B-frags hi, all iters
    __shared__ __align__(16) short8 xbl[12][192];           // x B-frags lo
    __shared__ __align__(16) unsigned short hbh[2][2048];   // h B-frags hi (pp)
    __shared__ __align__(16) unsigned short hbl[2][2048];   // h B-frags lo (pp)
    __shared__ int sdur[16], sstart[16];

    int tid  = threadIdx.x;
    int wave = tid >> 6, lane = tid & 63;
    int quad = lane >> 4, seg = lane & 15;

    if (tid < 16) {
        int ss = s0 + tid;
        sdur[tid]   = (ss < SS) ? dur_all[b * SS + ss] : 0;
        sstart[tid] = (ss < SS) ? starts[b * SS + ss]  : 0;
    }
    for (int i = tid; i < 2048; i += 512) { hbh[0][i] = 0; hbl[0][i] = 0; }

    // ---- w_hh A-frags (taus wave, wave+8, wave+16), persist in regs ----
    short8 Ah[3][4], Al[3][4];
    const short8* wph8 = (const short8*)wph;
    const short8* wpl8 = (const short8*)wpl;
#pragma unroll
    for (int tt = 0; tt < 3; tt++)
#pragma unroll
        for (int k32 = 0; k32 < 4; k32++) {
            int idx = ((dir * 24 + wave + 8 * tt) * 4 + k32) * 64 + lane;
            Ah[tt][k32] = wph8[idx];
            Al[tt][k32] = wpl8[idx];
        }
    // ---- w_ih A-frags (same taus, K=96), persist in regs ----
    short8 Gh[3][3], Gl[3][3];
    const short8* wih_h8 = (const short8*)wih_h;
    const short8* wih_l8 = (const short8*)wih_l;
#pragma unroll
    for (int tt = 0; tt < 3; tt++)
#pragma unroll
        for (int ks = 0; ks < 3; ks++) {
            int idx = ((dir * 24 + wave + 8 * tt) * 3 + ks) * 64 + lane;
            Gh[tt][ks] = wih_h8[idx];
            Gl[tt][ks] = wih_l8[idx];
        }

    // ---- per-lane meta & biases ----
    int s = s0 + seg;
    int sd = (s < SS) ? dur_all[b * SS + s] : 0;
    int slb = src_len[b];
    const float* bih = biasc + dir * G3;
    const float* bhh = dir ? bhb : bhf;
    int j0 = wave * 16 + quad * 4;
    float4 i_r = *(const float4*)&bih[j0];
    float4 i_z = *(const float4*)&bih[DMC + j0];
    float4 bxn = *(const float4*)&bih[2 * DMC + j0];
    float4 h_r = *(const float4*)&bhh[j0];
    float4 h_z = *(const float4*)&bhh[DMC + j0];
    float4 bhn = *(const float4*)&bhh[2 * DMC + j0];
    float4 br = make_float4(i_r.x + h_r.x, i_r.y + h_r.y, i_r.z + h_r.z, i_r.w + h_r.w);
    float4 bz = make_float4(i_z.x + h_z.x, i_z.y + h_z.y, i_z.z + h_z.z, i_z.w + h_z.w);
    float4 h = make_float4(0.f, 0.f, 0.f, 0.f);

    int idx8 = (j0 >> 5) * 64 + ((j0 >> 3) & 3) * 16 + seg;
    int wbase = idx8 * 8 + (j0 & 7);             // h-frag write addr (shorts)

    __syncthreads();   // sdur/sstart + h[0] frags visible

    // ---- stage ALL x B-frags (12 iters x 192 frag-lanes = 2304 tasks) ----
#pragma unroll
    for (int q = 0; q < 5; q++) {
        int u = tid + q * 512;
        if (u < 12 * 192) {
            int it  = u / 192;
            int rem = u - it * 192;
            int ks = rem >> 6, ln = rem & 63;
            int sg = ln & 15, qq = ln >> 4;
            int kb = ks * 32 + qq * 8;
            short8 hi8 = {0,0,0,0,0,0,0,0}, lo8 = {0,0,0,0,0,0,0,0};
            int d2 = sdur[sg];
            if (kb < NM && it < d2) {
                int t = dir ? (sstart[sg] + d2 - 1 - it) : (sstart[sg] + it);
                const float* xr = x + (size_t)(b * TT + t) * NM + kb;
#pragma unroll
                for (int j = 0; j < 8; j++) {
                    float v = xr[j];
                    unsigned short hi = f2bf(v);
                    hi8[j] = (short)hi;
                    lo8[j] = (short)f2bf(v - __uint_as_float(((unsigned)hi) << 16));
                }
            }
            xbh[it][rem] = hi8;
            xbl[it][rem] = lo8;
        }
    }
    __syncthreads();

    for (int i = 0; i < 12; i++) {
        int p = i & 1;
        bool act = (i < sd);

        // ---- MFMA: 6 independent accumulator chains (x: 9 ea, h: 12 ea) ----
        f32x4 axr = (f32x4){0.f,0.f,0.f,0.f};
        f32x4 axz = (f32x4){0.f,0.f,0.f,0.f};
        f32x4 axn = (f32x4){0.f,0.f,0.f,0.f};
        f32x4 ahr = (f32x4){0.f,0.f,0.f,0.f};
        f32x4 ahz = (f32x4){0.f,0.f,0.f,0.f};
        f32x4 ahn = (f32x4){0.f,0.f,0.f,0.f};
#pragma unroll
        for (int ks = 0; ks < 3; ks++) {
            short8 Bxh = xbh[i][ks * 64 + lane];
            short8 Bxl = xbl[i][ks * 64 + lane];
            axr = __builtin_amdgcn_mfma_f32_16x16x32_bf16(Gh[0][ks], Bxh, axr, 0, 0, 0);
            axr = __builtin_amdgcn_mfma_f32_16x16x32_bf16(Gh[0][ks], Bxl, axr, 0, 0, 0);
            axr = __builtin_amdgcn_mfma_f32_16x16x32_bf16(Gl[0][ks], Bxh, axr, 0, 0, 0);
            axz = __builtin_amdgcn_mfma_f32_16x16x32_bf16(Gh[1][ks], Bxh, axz, 0, 0, 0);
            axz = __builtin_amdgcn_mfma_f32_16x16x32_bf16(Gh[1][ks], Bxl, axz, 0, 0, 0);
            axz = __builtin_amdgcn_mfma_f32_16x16x32_bf16(Gl[1][ks], Bxh, axz, 0, 0, 0);
            axn = __builtin_amdgcn_mfma_f32_16x16x32_bf16(Gh[2][ks], Bxh, axn, 0, 0, 0);
            axn = __builtin_amdgcn_mfma_f32_16x16x32_bf16(Gh[2][ks], Bxl, axn, 0, 0, 0);
            axn = __builtin_amdgcn_mfma_f32_16x16x32_bf16(Gl[2][ks], Bxh, axn, 0, 0, 0);
        }
#pragma unroll
        for (int k32 = 0; k32 < 4; k32++) {
            short8 Bh = ((const short8*)hbh[p])[k32 * 64 + lane];
            short8 Bl = ((const short8*)hbl[p])[k32 * 64 + lane];
            ahr = __builtin_amdgcn_mfma_f32_16x16x32_bf16(Ah[0][k32], Bh, ahr, 0, 0, 0);
            ahr = __builtin_amdgcn_mfma_f32_16x16x32_bf16(Ah[0][k32], Bl, ahr, 0, 0, 0);
            ahr = __builtin_amdgcn_mfma_f32_16x16x32_bf16(Al[0][k32], Bh, ahr, 0, 0, 0);
            ahz = __builtin_amdgcn_mfma_f32_16x16x32_bf16(Ah[1][k32], Bh, ahz, 0, 0, 0);
            ahz = __builtin_amdgcn_mfma_f32_16x16x32_bf16(Ah[1][k32], Bl, ahz, 0, 0, 0);
            ahz = __builtin_amdgcn_mfma_f32_16x16x32_bf16(Al[1][k32], Bh, ahz, 0, 0, 0);
            ahn = __builtin_amdgcn_mfma_f32_16x16x32_bf16(Ah[2][k32], Bh, ahn, 0, 0, 0);
            ahn = __builtin_amdgcn_mfma_f32_16x16x32_bf16(Ah[2][k32], Bl, ahn, 0, 0, 0);
            ahn = __builtin_amdgcn_mfma_f32_16x16x32_bf16(Al[2][k32], Bh, ahn, 0, 0, 0);
        }

        // ---- lane-local GRU update ----
        if (act) {
            float hv[4]  = {h.x, h.y, h.z, h.w};
            float brv[4] = {br.x, br.y, br.z, br.w};
            float bzv[4] = {bz.x, bz.y, bz.z, bz.w};
            float bxv[4] = {bxn.x, bxn.y, bxn.z, bxn.w};
            float bhv[4] = {bhn.x, bhn.y, bhn.z, bhn.w};
#pragma unroll
            for (int cmp = 0; cmp < 4; cmp++) {
                float r = sigmoid_(axr[cmp] + ahr[cmp] + brv[cmp]);
                float z = sigmoid_(axz[cmp] + ahz[cmp] + bzv[cmp]);
                float n = tanh_(axn[cmp] + bxv[cmp] + r * (ahn[cmp] + bhv[cmp]));
                hv[cmp] = (1.f - z) * n + z * hv[cmp];
            }
            h = make_float4(hv[0], hv[1], hv[2], hv[3]);
            if (i == sd - 1) {
                float4 vout = (s < slb) ? h : make_float4(0.f, 0.f, 0.f, 0.f);
                *(float4*)&out[(b * SS + s) * (2 * DMC) + dir * DMC + j0] = vout;
            }
        }

        // ---- write h frags (split-bf16) to the other buffer ----
        {
            float hv[4] = {h.x, h.y, h.z, h.w};
            unsigned short hs_[4], ls_[4];
#pragma unroll
            for (int cmp = 0; cmp < 4; cmp++) {
                unsigned short hi = f2bf(hv[cmp]);
                float hif = __uint_as_float(((unsigned)hi) << 16);
                hs_[cmp] = hi;
                ls_[cmp] = f2bf(hv[cmp] - hif);
            }
            *(ushort4*)&hbh[1 - p][wbase] = make_ushort4(hs_[0], hs_[1], hs_[2], hs_[3]);
            *(ushort4*)&hbl[1 - p][wbase] = make_ushort4(ls_[0], ls_[1], ls_[2], ls_[3]);
        }
        __syncthreads();
    }
}

// ---------------------------------------------------------------------------
extern "C" void kernel_launch(void* const* d_in, const int* in_sizes, int n_in,
                              void* d_out, int out_size, void* d_ws, size_t ws_size,
                              hipStream_t stream) {
    const float* mel      = (const float*)d_in[0];
    const int*   durations= (const int*)  d_in[1];
    const int*   mel_len  = (const int*)  d_in[2];
    const int*   src_len  = (const int*)  d_in[3];
    const float* w1       = (const float*)d_in[4];
    const float* g1       = (const float*)d_in[5];
    const float* be1      = (const float*)d_in[6];
    const float* w2       = (const float*)d_in[7];
    const float* g2       = (const float*)d_in[8];
    const float* be2      = (const float*)d_in[9];
    const float* w_ih_f   = (const float*)d_in[10];
    const float* w_hh_f   = (const float*)d_in[11];
    const float* b_ih_f   = (const float*)d_in[12];
    const float* b_hh_f   = (const float*)d_in[13];
    const float* w_ih_b   = (const float*)d_in[14];
    const float* w_hh_b   = (const float*)d_in[15];
    const float* b_ih_b   = (const float*)d_in[16];
    const float* b_hh_b   = (const float*)d_in[17];
    float* out = (float*)d_out;

    // workspace: x | wph | wpl | wih_h | wih_l | biasc | starts
    float* x    = (float*)d_ws;
    unsigned short* wph   = (unsigned short*)(x + NROW * NM);
    unsigned short* wpl   = wph + 2 * 24 * 4 * 64 * 8;
    unsigned short* wih_h = wpl + 2 * 24 * 4 * 64 * 8;
    unsigned short* wih_l = wih_h + 48 * 3 * 64 * 8;
    float* biasc = (float*)(wih_l + 48 * 3 * 64 * 8);
    int*   starts= (int*)(biasc + 768);

    k_prep<<<22, 1024, 0, stream>>>(w_hh_f, w_hh_b, w_ih_f, w_ih_b, b_ih_f, b_ih_b,
                                    durations, wph, wpl, wih_h, wih_l, biasc, starts);
    k_conv<<<dim3(TT / 2, BB), 256, 0, stream>>>(mel, mel_len, w1, g1, be1, w2, g2, be2, x);
    k_gru<<<dim3(7, 8, 2), 512, 0, stream>>>(x, wph, wpl, wih_h, wih_l, biasc,
                                             durations, starts, src_len,
                                             b_hh_f, b_hh_b, out);
}